// Round 1
// baseline (4713.284 us; speedup 1.0000x reference)
//
#include <hip/hip_runtime.h>
#include <hip/hip_bf16.h>
#include <math.h>

// Problem constants
#define Bc 2
#define Lc 2048
#define Dc 4096
#define DZc 1024
#define Hc 16
#define HDc 64

// Output layout (flat float32, in reference return order)
#define OFF_OUT   0L
#define OFF_Z     16777216L    // (2,2048,4096)
#define OFF_KR    20971520L    // (2,2048,1024)
#define OFF_ATTN  25165824L    // (2,16,2048,2048)
#define OFF_SC    159383552L   // (2,16,2048,2048)

#define TS 64
#define KC 32
#define LDP (TS + 4)   // pad to 68 floats: rows stay 16B-aligned, conflicts <=2-way (free)

// Generic fp32 GEMM: C = A @ B (+bias), optional transB, optional causal mask epilogue,
// optional batching with base = (bz/Hdiv)*s1 + (bz%Hdiv)*s2 for A/B/C.
__global__ __launch_bounds__(256) void gemm_f32(
    const float* __restrict__ A, const float* __restrict__ Bp,
    const float* __restrict__ bias, float* __restrict__ C,
    int M, int N, int K, int lda, int ldb, int ldc,
    long sA1, long sA2, long sB1, long sB2, long sC1, long sC2,
    int Hdiv, int transB, int causal, float scale, float maskval)
{
    __shared__ float As[KC][LDP];  // As[k][m]  (A tile stored transposed)
    __shared__ float Bs[KC][LDP];  // Bs[k][n]

    const int bz = blockIdx.z;
    const long ab = (long)(bz / Hdiv) * sA1 + (long)(bz % Hdiv) * sA2;
    const long bb = (long)(bz / Hdiv) * sB1 + (long)(bz % Hdiv) * sB2;
    const long cb = (long)(bz / Hdiv) * sC1 + (long)(bz % Hdiv) * sC2;
    const float* Ab = A + ab;
    const float* Bb = Bp + bb;
    float* Cb = C + cb;

    const int m0 = blockIdx.y * TS;
    const int n0 = blockIdx.x * TS;
    const int t  = threadIdx.x;
    const int tx = t & 15, ty = t >> 4;

    // Fully-masked causal tile: skip compute, just fill.
    if (causal && n0 > m0 + TS - 1) {
        for (int e = 0; e < 16; ++e) {
            int i = e * 256 + t;
            int r = i >> 6, c = i & 63;
            Cb[(long)(m0 + r) * ldc + (n0 + c)] = maskval;
        }
        return;
    }

    float acc[4][4] = {};

    for (int k0 = 0; k0 < K; k0 += KC) {
        // A tile: 64 rows (m) x 32 cols (k) -> As[k][m]
        for (int e = 0; e < 8; ++e) {
            int i = e * 256 + t;
            int r = i >> 5, c = i & 31;
            As[c][r] = Ab[(long)(m0 + r) * lda + (k0 + c)];
        }
        if (!transB) {
            // B tile: 32 rows (k) x 64 cols (n)
            for (int e = 0; e < 8; ++e) {
                int i = e * 256 + t;
                int r = i >> 6, c = i & 63;
                Bs[r][c] = Bb[(long)(k0 + r) * ldb + (n0 + c)];
            }
        } else {
            // B rows are n, cols are k: Bs[k][n] = Bp[n*ldb + k]
            for (int e = 0; e < 8; ++e) {
                int i = e * 256 + t;
                int r = i >> 5, c = i & 31;
                Bs[c][r] = Bb[(long)(n0 + r) * ldb + (k0 + c)];
            }
        }
        __syncthreads();
        for (int kk = 0; kk < KC; ++kk) {
            float4 av = *(const float4*)&As[kk][ty * 4];
            float4 bv = *(const float4*)&Bs[kk][tx * 4];
            float a0[4] = {av.x, av.y, av.z, av.w};
            float b0[4] = {bv.x, bv.y, bv.z, bv.w};
#pragma unroll
            for (int i = 0; i < 4; ++i)
#pragma unroll
                for (int j = 0; j < 4; ++j)
                    acc[i][j] = fmaf(a0[i], b0[j], acc[i][j]);
        }
        __syncthreads();
    }

    for (int i = 0; i < 4; ++i) {
        int m = m0 + ty * 4 + i;
        for (int j = 0; j < 4; ++j) {
            int n = n0 + tx * 4 + j;
            float v = acc[i][j] * scale;
            if (bias) v += bias[n];
            if (causal && n > m) v = maskval;
            Cb[(long)m * ldc + n] = v;
        }
    }
}

// RoPE over (B,L,H,64): out[i] = x[i]*cos - x[i+32]*sin ; out[i+32] = x[i+32]*cos + x[i]*sin
// in/out1 may alias (each thread reads its pair before writing). out2 optional second sink.
__global__ __launch_bounds__(256) void rope_kernel(
    const float* in, int in_ld, float* out1, int out1_ld, float* out2, int out2_ld)
{
    int t = blockIdx.x * 256 + threadIdx.x;   // B*L*H*32 = 2,097,152 threads
    int i = t & 31;
    int h = (t >> 5) & 15;
    int l = (t >> 9) & 2047;
    int b = t >> 20;
    long row = (long)b * Lc + l;

    float inv_freq = powf(10000.0f, -(float)i * (1.0f / 32.0f));
    float ang = (float)l * inv_freq;
    float s, c;
    sincosf(ang, &s, &c);

    long i1 = row * in_ld + h * 64 + i;
    long i2 = i1 + 32;
    float x1 = in[i1], x2 = in[i2];
    float o1 = x1 * c - x2 * s;
    float o2 = x2 * c + x1 * s;
    long o1a = row * out1_ld + h * 64 + i;
    out1[o1a] = o1;
    out1[o1a + 32] = o2;
    if (out2) {
        long o2a = row * out2_ld + h * 64 + i;
        out2[o2a] = o1;
        out2[o2a + 32] = o2;
    }
}

// Row softmax over 2048-wide rows. One block (256 threads, 8 elems/thread) per row.
__global__ __launch_bounds__(256) void softmax_kernel(
    const float* __restrict__ S, float* __restrict__ P)
{
    long row = blockIdx.x;
    const float* sr = S + row * Lc;
    float* pr = P + row * Lc;
    int t = threadIdx.x;

    float v[8];
    float m = -3.4e38f;
#pragma unroll
    for (int e = 0; e < 8; ++e) { v[e] = sr[t + e * 256]; m = fmaxf(m, v[e]); }
#pragma unroll
    for (int off = 32; off >= 1; off >>= 1) m = fmaxf(m, __shfl_xor(m, off));
    __shared__ float redm[4], reds[4];
    int wave = t >> 6;
    if ((t & 63) == 0) redm[wave] = m;
    __syncthreads();
    m = fmaxf(fmaxf(redm[0], redm[1]), fmaxf(redm[2], redm[3]));

    float s = 0.0f;
#pragma unroll
    for (int e = 0; e < 8; ++e) { v[e] = __expf(v[e] - m); s += v[e]; }
#pragma unroll
    for (int off = 32; off >= 1; off >>= 1) s += __shfl_xor(s, off);
    if ((t & 63) == 0) reds[wave] = s;
    __syncthreads();
    s = reds[0] + reds[1] + reds[2] + reds[3];
    float inv = 1.0f / s;
#pragma unroll
    for (int e = 0; e < 8; ++e) pr[t + e * 256] = v[e] * inv;
}

extern "C" void kernel_launch(void* const* d_in, const int* in_sizes, int n_in,
                              void* d_out, int out_size, void* d_ws, size_t ws_size,
                              hipStream_t stream)
{
    const float* x        = (const float*)d_in[0];
    const float* W_latent = (const float*)d_in[1];
    const float* W_q_down = (const float*)d_in[2];
    const float* b_q_down = (const float*)d_in[3];
    const float* W_q_up   = (const float*)d_in[4];
    const float* W_k_up   = (const float*)d_in[5];
    const float* W_v_up   = (const float*)d_in[6];
    const float* W_x_rope = (const float*)d_in[7];
    const float* W_k_rope = (const float*)d_in[8];
    const float* W_o      = (const float*)d_in[9];

    float* out       = (float*)d_out;
    float* z_out     = out + OFF_Z;
    float* kr_out    = out + OFF_KR;
    float* attn_out  = out + OFF_ATTN;
    float* sc_out    = out + OFF_SC;

    // Workspace layout (floats). q_lat aliased with head_out (lifetimes disjoint).
    float* ws   = (float*)d_ws;
    float* qlat = ws;                       // 4,194,304  (also reused as ho later)
    float* qcat = ws + 4194304;             // 8,388,608  (B,L,2048): [query | q_rope]
    float* kcat = qcat + 8388608;           // 8,388,608  (B,L,2048): [key_nope | key_rope]
    float* val  = kcat + 8388608;           // 4,194,304  (B,L,1024)
    float* ho   = qlat;                     // alias: q_lat dead before ho written
    // total: 25,165,824 floats = 96 MB <= ws_size (assumed)

    const int M = Bc * Lc;  // 4096

    auto gemm = [&](const float* A, const float* Bp, const float* bias, float* C,
                    int Mm, int N, int K, int lda, int ldb, int ldc,
                    long sA1, long sA2, long sB1, long sB2, long sC1, long sC2,
                    int Hdiv, int batch, int transB, int causal, float scale, float maskval) {
        dim3 g(N / TS, Mm / TS, batch);
        gemm_f32<<<g, dim3(256), 0, stream>>>(A, Bp, bias, C, Mm, N, K, lda, ldb, ldc,
                                              sA1, sA2, sB1, sB2, sC1, sC2,
                                              Hdiv, transB, causal, scale, maskval);
    };

    // 1. z = x @ W_latent                        -> d_out z region
    gemm(x, W_latent, nullptr, z_out, M, DZc, Dc, Dc, DZc, DZc,
         0, 0, 0, 0, 0, 0, 1, 1, 0, 0, 1.0f, 0.0f);
    // 2. q_lat = x @ W_q_down + b_q_down         -> ws
    gemm(x, W_q_down, b_q_down, qlat, M, DZc, Dc, Dc, DZc, DZc,
         0, 0, 0, 0, 0, 0, 1, 1, 0, 0, 1.0f, 0.0f);
    // 3. kr_pre = x @ W_k_rope                   -> kcat cols [1024:2048]
    gemm(x, W_k_rope, nullptr, kcat + 1024, M, DZc, Dc, Dc, DZc, 2048,
         0, 0, 0, 0, 0, 0, 1, 1, 0, 0, 1.0f, 0.0f);
    // 4. rope(k): in-place in kcat + copy to d_out key_rope
    rope_kernel<<<dim3(8192), dim3(256), 0, stream>>>(kcat + 1024, 2048, kcat + 1024, 2048, kr_out, 1024);
    // 5. key_nope = z @ W_k_up                   -> kcat cols [0:1024]
    gemm(z_out, W_k_up, nullptr, kcat, M, DZc, DZc, DZc, DZc, 2048,
         0, 0, 0, 0, 0, 0, 1, 1, 0, 0, 1.0f, 0.0f);
    // 6. value = z @ W_v_up                      -> ws
    gemm(z_out, W_v_up, nullptr, val, M, DZc, DZc, DZc, DZc, DZc,
         0, 0, 0, 0, 0, 0, 1, 1, 0, 0, 1.0f, 0.0f);
    // 7. query = q_lat @ W_q_up                  -> qcat cols [0:1024]
    gemm(qlat, W_q_up, nullptr, qcat, M, DZc, DZc, DZc, DZc, 2048,
         0, 0, 0, 0, 0, 0, 1, 1, 0, 0, 1.0f, 0.0f);
    // 8. qr_pre = q_lat @ W_x_rope               -> qcat cols [1024:2048]
    gemm(qlat, W_x_rope, nullptr, qcat + 1024, M, DZc, DZc, DZc, DZc, 2048,
         0, 0, 0, 0, 0, 0, 1, 1, 0, 0, 1.0f, 0.0f);
    // 9. rope(q): in-place in qcat
    rope_kernel<<<dim3(8192), dim3(256), 0, stream>>>(qcat + 1024, 2048, qcat + 1024, 2048, nullptr, 0);
    // 10. scores = Q @ K^T / sqrt(128), causal -1e6   (head h = contiguous 128 dims of concat)
    gemm(qcat, kcat, nullptr, sc_out, Lc, Lc, 2 * HDc, 2048, 2048, Lc,
         (long)Lc * 2048, 128, (long)Lc * 2048, 128, (long)Hc * Lc * Lc, (long)Lc * Lc,
         Hc, Bc * Hc, 1, 1, 0.08838834764831845f, -1e6f);
    // 11. attn_weights = softmax(scores)
    softmax_kernel<<<dim3(Bc * Hc * Lc), dim3(256), 0, stream>>>(sc_out, attn_out);
    // 12. head_out = scores @ value   (reference uses masked scores, NOT attn_weights)
    gemm(sc_out, val, nullptr, ho, Lc, HDc, Lc, Lc, DZc, DZc,
         (long)Hc * Lc * Lc, (long)Lc * Lc, (long)Lc * DZc, 64, (long)Lc * DZc, 64,
         Hc, Bc * Hc, 0, 0, 1.0f, 0.0f);
    // 13. out = head_out @ W_o
    gemm(ho, W_o, nullptr, out, M, Dc, DZc, DZc, Dc, Dc,
         0, 0, 0, 0, 0, 0, 1, 1, 0, 0, 1.0f, 0.0f);
}